// Round 7
// baseline (503.166 us; speedup 1.0000x reference)
//
#include <hip/hip_runtime.h>
#include <hip/hip_bf16.h>
#include <stdint.h>

// GAT forward, N=8192, IN=256, OUT=128. Inputs fp32 (adj int32), output fp32.
// softmax_j(a1_i + a2_j | adj) == adj_ij*exp(a2_j)/sum_j adj_ij*exp(a2_j)  (a1 cancels)
// -> out = (adj @ (w*h)) / (adj @ w), with w=exp(h.a2w+a2b), h=F@W+b.
// v10 = v9 PROBE ROUND: k_agg launched 4x (idempotent producer -> semantics
// unchanged). Total-dur delta vs R6's 431us = 3 x T_agg, giving exact attribution
// that rocprof can't (all kernels < 157us fill cutoff). R0-R6 ledger: fill ~159us
// is inside the timed window (R0 fit: 461 = 160 fill + 173 agg + 114 h_fused + 14);
// R6 controllables sum to ~272us vs ~70us combined floor -- either agg_v9 is still
// ~115us (phase model wrong) or hW+adjbits own ~250us. This round decides.
//   k_hW:      h/w/whB VALU kernel (unchanged).
//   k_adjbits: adj int32 -> 8 MB bitmask (unchanged).
//   k_agg x4:  LDS-staged bitmask x whB -> per-wave partials P (unchanged kernel).
//   k_epi:     reduce 8 ksplit-partials + divide (unchanged).

typedef __attribute__((ext_vector_type(8))) short short8;
typedef __attribute__((ext_vector_type(4))) float float4v;

static __device__ __forceinline__ unsigned short f2bf(float f) {
    union { float f; uint32_t i; } v; v.f = f;
    uint32_t r = v.i + 0x7FFFu + ((v.i >> 16) & 1u);
    return (unsigned short)(r >> 16);
}

// round fp32 to bf16 precision, keep as fp32 (matches MFMA-bf16 numerics)
static __device__ __forceinline__ float bfr(float x) {
    union { float f; uint32_t u; } v; v.f = x;
    uint32_t r = (v.u + 0x7FFFu + ((v.u >> 16) & 1u)) & 0xFFFF0000u;
    union { uint32_t u; float f; } o; o.u = r;
    return o.f;
}

// expand 8 bits -> 8 packed bf16 {0.0, 1.0}.
static __device__ __forceinline__ short8 expand8(uint32_t B) {
    uint64_t S = ((uint64_t)B * 0x8040201008040201ull >> 7) & 0x0101010101010101ull;
    uint32_t lo = (uint32_t)S;          // bytes {b7,b6,b5,b4}
    uint32_t hi = (uint32_t)(S >> 32);  // bytes {b3,b2,b1,b0}
    union { uint32_t u[4]; short8 s; } r;
    r.u[0] = ((hi >> 24) | (((hi >> 16) & 0xFFu) << 16)) * 0x3F80u;  // e0,e1
    r.u[1] = (((hi >> 8) & 0xFFu) | ((hi & 0xFFu) << 16)) * 0x3F80u; // e2,e3
    r.u[2] = ((lo >> 24) | (((lo >> 16) & 0xFFu) << 16)) * 0x3F80u;  // e4,e5
    r.u[3] = (((lo >> 8) & 0xFFu) | ((lo & 0xFFu) << 16)) * 0x3F80u; // e6,e7
    return r.s;
}

// async global->LDS, 16 B per lane. LDS dest is (wave-uniform base + lane*16);
// all call sites satisfy this by construction. Global src is per-lane arbitrary.
static __device__ __forceinline__ void gl_lds16(const void* g, void* l) {
    __builtin_amdgcn_global_load_lds(
        (const __attribute__((address_space(1))) uint32_t*)g,
        (__attribute__((address_space(3))) uint32_t*)l, 16, 0, 0);
}

// ---- prepass: adj int32 -> bitmask. 4096 blocks x 256 (wave = half a row). ----
__global__ __launch_bounds__(256) void k_adjbits(const int* __restrict__ adj,
                                                 uint32_t* __restrict__ adjb) {
    int t = threadIdx.x, lane = t & 63;
    int wv = blockIdx.x * 4 + (t >> 6);           // 0..16383
    int row = wv >> 1, half = wv & 1;
    const int4* p = reinterpret_cast<const int4*>(adj + (size_t)row * 8192 + half * 4096) + lane;
    uint32_t* ob = adjb + (size_t)row * 256 + half * 128;
    #pragma unroll 4
    for (int kk = 0; kk < 16; kk++) {
        int4 v = p[kk * 64];
        uint32_t nib = (v.x != 0 ? 1u : 0u) | (v.y != 0 ? 2u : 0u) |
                       (v.z != 0 ? 4u : 0u) | (v.w != 0 ? 8u : 0u);
        uint32_t q = nib | (((uint32_t)__shfl_xor((int)nib, 1)) << 4);
        q |= ((uint32_t)__shfl_xor((int)q, 2)) << 8;
        q |= ((uint32_t)__shfl_xor((int)q, 4)) << 16;
        if ((lane & 7) == 0) ob[kk * 8 + (lane >> 3)] = q;
    }
}

// ---- h = F@W+b, w = exp(h.a2w+a2b), emit fragment-major whB ----
__global__ __launch_bounds__(256) void k_hW(const float* __restrict__ F,
                                            const float* __restrict__ W,
                                            const float* __restrict__ bvec,
                                            const float* __restrict__ a2w,
                                            const float* __restrict__ a2b,
                                            unsigned short* __restrict__ whB) {
    __shared__ float Fs[32 * 256];     // 32 KB
    __shared__ float Ws[64 * 128];     // 32 KB (one kt-chunk of W)
    __shared__ float bs[128], aws[128], wls[32];
    __shared__ float ab_s;

    int t = threadIdx.x;
    int row = t >> 3, g = t & 7;
    int ig = blockIdx.x, j0 = ig * 32;

    if (t < 128) { bs[t] = bvec[t]; aws[t] = a2w[t]; }
    if (t == 0) ab_s = a2b[0];

    #pragma unroll
    for (int i = 0; i < 8; i++) {
        int flat = t + 256 * i;                   // float4 index
        int fr = flat >> 6, fp_ = (flat & 63) << 2;
        float4 v = *reinterpret_cast<const float4*>(F + (size_t)(j0 + fr) * 256 + fp_);
        float4 o; o.x = bfr(v.x); o.y = bfr(v.y); o.z = bfr(v.z); o.w = bfr(v.w);
        *reinterpret_cast<float4*>(&Fs[fr * 256 + fp_]) = o;
    }

    float h[16];
    #pragma unroll
    for (int i = 0; i < 16; i++) h[i] = 0.0f;

    for (int kt = 0; kt < 4; kt++) {
        if (kt) __syncthreads();
        #pragma unroll
        for (int i = 0; i < 8; i++) {
            int flat = t + 256 * i;
            int wr = flat >> 5, wp = (flat & 31) << 2;
            float4 v = *reinterpret_cast<const float4*>(W + (size_t)(kt * 64 + wr) * 128 + wp);
            float4 o; o.x = bfr(v.x); o.y = bfr(v.y); o.z = bfr(v.z); o.w = bfr(v.w);
            *reinterpret_cast<float4*>(&Ws[wr * 128 + wp]) = o;
        }
        __syncthreads();
        for (int kk = 0; kk < 64; kk++) {
            float f = Fs[row * 256 + kt * 64 + kk];
            #pragma unroll
            for (int i = 0; i < 16; i++)
                h[i] += f * Ws[kk * 128 + g * 16 + i];
        }
    }

    float part = 0.0f;
    #pragma unroll
    for (int i = 0; i < 16; i++) {
        h[i] += bs[g * 16 + i];
        part += h[i] * aws[g * 16 + i];
    }
    part += __shfl_xor(part, 1);
    part += __shfl_xor(part, 2);
    part += __shfl_xor(part, 4);
    float wv = expf(fminf(fmaxf(part + ab_s, -60.0f), 60.0f));
    if (g == 0) wls[row] = wv;

    // whB record (ig,c): lane l=(kq,m), elem r holds B[k=ig*32+kq*8+r][c*16+m].
    int kq = row >> 3, r = row & 7;
    #pragma unroll
    for (int i = 0; i < 16; i++) {
        unsigned short u = f2bf(h[i] * wv);
        whB[((size_t)(ig * 9 + g) * 64 + kq * 16 + i) * 8 + r] = u;
    }
    __syncthreads();
    if (t < 64) {
        int m0 = t & 15, kq2 = t >> 4;
        uint4 val = make_uint4(0u, 0u, 0u, 0u);
        if (m0 == 0) {
            uint32_t u0 = (uint32_t)f2bf(wls[kq2 * 8 + 0]) | ((uint32_t)f2bf(wls[kq2 * 8 + 1]) << 16);
            uint32_t u1 = (uint32_t)f2bf(wls[kq2 * 8 + 2]) | ((uint32_t)f2bf(wls[kq2 * 8 + 3]) << 16);
            uint32_t u2 = (uint32_t)f2bf(wls[kq2 * 8 + 4]) | ((uint32_t)f2bf(wls[kq2 * 8 + 5]) << 16);
            uint32_t u3 = (uint32_t)f2bf(wls[kq2 * 8 + 6]) | ((uint32_t)f2bf(wls[kq2 * 8 + 7]) << 16);
            val = make_uint4(u0, u1, u2, u3);
        }
        *reinterpret_cast<uint4*>(whB + ((size_t)(ig * 9 + 8) * 64 + t) * 8) = val;
    }
}

// ---- KMAIN v9: LDS-staged, double-buffered (unchanged from R6) ----
__global__ __launch_bounds__(256) void k_agg(const uint32_t* __restrict__ adjb,
                                             const unsigned short* __restrict__ whB,
                                             float* __restrict__ P) {
    __shared__ __align__(16) unsigned short Bs[2][36 * 512];   // 2 x 36,864 B
    __shared__ __align__(16) uint32_t Ab[2][512];              // 2 x  2,048 B

    int t = threadIdx.x;
    int w = t >> 6, lane = t & 63;
    int m = lane & 15, kq = lane >> 4;
    int blk = blockIdx.x;
    int bigrs = blk >> 3, ksplit = blk & 7;       // 64 rowsets x 8 ksplits
    int rb = bigrs * 128;
    int w32 = w * 32;
    uint32_t sh = (uint32_t)kq * 8;

    float4v acc[2][9];
    #pragma unroll
    for (int s = 0; s < 2; s++)
        for (int c = 0; c < 9; c++) acc[s][c] = (float4v)0.0f;

    auto stage = [&](int ph, int b) {
        const unsigned short* gB = whB + (size_t)(ksplit * 32 + ph * 4) * 9 * 512;
        #pragma unroll
        for (int s = 0; s < 9; s++)
            gl_lds16(gB + (size_t)(s * 256 + t) * 8, &Bs[b][(s * 256 + t) * 8]);
        if (t < 128)
            gl_lds16(adjb + (size_t)(rb + t) * 256 + ksplit * 32 + ph * 4, &Ab[b][t * 4]);
    };

    stage(0, 0);
    __syncthreads();

    for (int ph = 0; ph < 8; ph++) {
        int b = ph & 1;
        if (ph < 7) stage(ph + 1, b ^ 1);
        const unsigned short* bs = &Bs[b][0];
        const uint32_t* ab = &Ab[b][0];
        #pragma unroll
        for (int i4 = 0; i4 < 4; i4++) {
            uint32_t U0 = ab[(w32 + m) * 4 + i4];
            uint32_t U1 = ab[(w32 + 16 + m) * 4 + i4];
            short8 af0 = expand8((U0 >> sh) & 0xFFu);
            short8 af1 = expand8((U1 >> sh) & 0xFFu);
            #pragma unroll
            for (int c = 0; c < 9; c++) {
                short8 bf = *reinterpret_cast<const short8*>(&bs[(i4 * 9 + c) * 512 + lane * 8]);
                acc[0][c] = __builtin_amdgcn_mfma_f32_16x16x32_bf16(af0, bf, acc[0][c], 0, 0, 0);
                acc[1][c] = __builtin_amdgcn_mfma_f32_16x16x32_bf16(af1, bf, acc[1][c], 0, 0, 0);
            }
        }
        __syncthreads();
    }

    int wid = blk * 4 + w;                        // 0..2047
    float* o = P + (size_t)wid * 4608 + lane;
    #pragma unroll
    for (int s = 0; s < 2; s++)
        for (int c = 0; c < 9; c++)
            for (int rr = 0; rr < 4; rr++)
                o[((s * 9 + c) * 4 + rr) * 64] = acc[s][c][rr];
}

// ---- reduce 8 ksplit-partials + divide. 256 blocks (one 32-row rowset each). ----
__global__ __launch_bounds__(256) void k_epi(const float* __restrict__ P,
                                             float* __restrict__ out) {
    __shared__ float den[32];
    int t = threadIdx.x;
    int g = blockIdx.x;                           // 32-row rowset
    int big = g >> 2, w = g & 3;

    float r[18];
    #pragma unroll
    for (int i = 0; i < 18; i++) {
        int p = t + 256 * i;
        float s = 0.0f;
        #pragma unroll
        for (int ks = 0; ks < 8; ks++)
            s += P[(size_t)((big * 8 + ks) * 4 + w) * 4608 + p];
        r[i] = s;
        int instr = p >> 6, lane = p & 63;
        int sc = instr >> 2, rr = instr & 3;
        int c = sc % 9, ss = sc / 9;
        int m = lane & 15, kq = lane >> 4;
        if (c == 8 && m == 0) den[ss * 16 + kq * 4 + rr] = s;
    }
    __syncthreads();
    #pragma unroll
    for (int i = 0; i < 18; i++) {
        int p = t + 256 * i;
        int instr = p >> 6, lane = p & 63;
        int sc = instr >> 2, rr = instr & 3;
        int c = sc % 9, ss = sc / 9;
        int m = lane & 15, kq = lane >> 4;
        if (c < 8) {
            int jl = ss * 16 + kq * 4 + rr;
            out[((size_t)(g * 32 + jl)) * 128 + c * 16 + m] = r[i] / den[jl];
        }
    }
}

extern "C" void kernel_launch(void* const* d_in, const int* in_sizes, int n_in,
                              void* d_out, int out_size, void* d_ws, size_t ws_size,
                              hipStream_t stream) {
    const float* F   = (const float*)d_in[0];     // [8192][256]
    const int*   adj = (const int*)d_in[1];       // [8192][8192] 0/1
    const float* W   = (const float*)d_in[2];     // [256][128]
    const float* bv  = (const float*)d_in[3];     // [128]
    const float* a2w = (const float*)d_in[6];     // [128]  (a1 cancels; d_in[4],[5] unused)
    const float* a2b = (const float*)d_in[7];     // [1]
    float* out = (float*)d_out;                   // [8192][128]

    char* ws = (char*)d_ws;
    unsigned short* whB  = (unsigned short*)(ws);            //  2,359,296 B
    uint32_t*       adjb = (uint32_t*)(ws + 2359296);        //  8,388,608 B
    float*          P    = (float*)(ws + 10747904);          // 37,748,736 B (2048 x 4608 fp32)
                                                             // total 48,496,640

    k_hW<<<256, 256, 0, stream>>>(F, W, bv, a2w, a2b, whB);
    k_adjbits<<<4096, 256, 0, stream>>>(adj, adjb);
    // PROBE: k_agg x4 (idempotent). dur_delta vs R6 = 3 x T_agg.
    k_agg<<<512, 256, 0, stream>>>(adjb, whB, P);
    k_agg<<<512, 256, 0, stream>>>(adjb, whB, P);
    k_agg<<<512, 256, 0, stream>>>(adjb, whB, P);
    k_agg<<<512, 256, 0, stream>>>(adjb, whB, P);
    k_epi<<<256, 256, 0, stream>>>(P, out);
}